// Round 18
// baseline (274.365 us; speedup 1.0000x reference)
//
#include <hip/hip_runtime.h>
#include <hip/hip_fp16.h>

#define DEVI __device__ __forceinline__

typedef _Float16 f16;
typedef _Float16 f16x8 __attribute__((ext_vector_type(8)));
typedef _Float16 f16x4 __attribute__((ext_vector_type(4)));
typedef float    f32x4  __attribute__((ext_vector_type(4)));
typedef float    f32x16 __attribute__((ext_vector_type(16)));

DEVI float2 cmul(float2 a, float2 b){ return make_float2(fmaf(a.x,b.x,-(a.y*b.y)), fmaf(a.x,b.y,a.y*b.x)); }
DEVI float2 h2f2(__half2 v){ return make_float2(__low2float(v), __high2float(v)); }
DEVI __half2 f2h2(float a, float b){ return __floats2half2_rn(a, b); }
DEVI __half2 hswap(__half2 v){ __half2 r; r.x = v.y; r.y = v.x; return r; }
DEVI int rev4(int k){ return ((k&3)<<6) | (((k>>2)&3)<<4) | (((k>>4)&3)<<2) | ((k>>6)&3); }
// tanh-form GELU (max err ~3e-3). inf-safe via __expf.
DEVI float gelu(float v){
  const float u2 = 1.5957691216057308f*v*(1.0f + 0.044715f*v*v);
  const float e = __expf(u2);
  return v - v/(e + 1.0f);
}
DEVI float sshrink(float v){ return v > 0.01f ? v-0.01f : (v < -0.01f ? v+0.01f : 0.0f); }
// swzF: word-granule fold (x5 spreads bits[7:5] into [2:0]&[4:2]) + row-fold; W-FFT kernels only.
DEVI int swzF(int a){ return a ^ ((5*((a>>5)&7))&31) ^ ((a>>8)&31); }
DEVI f32x16 zero16(){
  f32x16 z;
#pragma unroll
  for (int i=0;i<16;++i) z[i]=0.f;
  return z;
}

// packed complex multiply by twiddle (c,d): re = x c - y d ; im = y c + x d
// cc = {c,c}, dd = {-d, +d}
DEVI __half2 cmulp(__half2 v, __half2 cc, __half2 dd){
  return __hfma2(v, cc, __hmul2(hswap(v), dd));
}

// In-place FFT over `rows` rows of 256 complex values (half2 in LDS, PACKED f16 math).
// DIR=-1: forward DIF (natural -> base-4 digit-reversed).
// DIR=+1: inverse DIT (digit-reversed -> natural, UNNORMALIZED).
// SW: 0 = none, 1 = swzF. Twiddles hoisted (lane-constant per stage), f32-generated.
template<int DIR, int SW>
DEVI void fft256(__half2* d, int rows, int tid, int nthr){
  const int w   = tid & 63;
  const int r0  = tid >> 6;
  const int rst = nthr >> 6;
  const __half2 NI = f2h2( 1.f,-1.f);   // mul by -i after swap
  const __half2 PI_= f2h2(-1.f, 1.f);   // mul by +i after swap
  #pragma unroll
  for (int si=0; si<4; ++si){
    const int lq = (DIR<0) ? (6-2*si) : (2*si);
    const int q4 = 1<<lq;
    const int j = w & (q4-1);
    const int blk = w >> lq;
    const int aoff = (blk<<(lq+2)) + j;
    const int e = j*(64>>lq);
    float sn, cs;
    __sincosf((float)(DIR*e) * 0.0245436926061703f, &sn, &cs);
    const float cs2 = cs*cs - sn*sn, sn2 = 2.f*cs*sn;
    const float cs3 = cs2*cs - sn2*sn, sn3 = sn2*cs + cs2*sn;
    const __half2 cc1 = f2h2(cs,cs),   dd1 = f2h2(-sn,sn);
    const __half2 cc2 = f2h2(cs2,cs2), dd2 = f2h2(-sn2,sn2);
    const __half2 cc3 = f2h2(cs3,cs3), dd3 = f2h2(-sn3,sn3);
    for (int r = r0; r < rows; r += rst){
      const int base = (r<<8) + aoff;
      const int a0 = SW ? swzF(base)        : base;
      const int a1 = SW ? swzF(base+q4)     : base+q4;
      const int a2 = SW ? swzF(base+2*q4)   : base+2*q4;
      const int a3 = SW ? swzF(base+3*q4)   : base+3*q4;
      if (DIR < 0){
        const __half2 x0=d[a0], x1=d[a1], x2=d[a2], x3=d[a3];
        const __half2 t0=__hadd2(x0,x2), t1=__hsub2(x0,x2), t2=__hadd2(x1,x3);
        const __half2 t3=__hmul2(hswap(__hsub2(x1,x3)), NI);
        d[a0] = __hadd2(t0,t2);
        d[a1] = cmulp(__hadd2(t1,t3), cc1, dd1);
        d[a2] = cmulp(__hsub2(t0,t2), cc2, dd2);
        d[a3] = cmulp(__hsub2(t1,t3), cc3, dd3);
      } else {
        const __half2 x0 = d[a0];
        const __half2 b1 = cmulp(d[a1], cc1, dd1);
        const __half2 b2 = cmulp(d[a2], cc2, dd2);
        const __half2 b3 = cmulp(d[a3], cc3, dd3);
        const __half2 t0=__hadd2(x0,b2), t1=__hsub2(x0,b2), t2=__hadd2(b1,b3);
        const __half2 t3=__hmul2(hswap(__hsub2(b1,b3)), PI_);
        d[a0] = __hadd2(t0,t2);
        d[a1] = __hadd2(t1,t3);
        d[a2] = __hsub2(t0,t2);
        d[a3] = __hsub2(t1,t3);
      }
    }
    __syncthreads();
  }
}

// ---------------- GEMM1 v6 (2 M-tiles/block, w staged once): h planar = gelu(p1w.x + p1b) ----------------
// grid 1024: each block does px tiles [pgB, pgB+128) and [pgB+128, pgB+256).
// buf aliases: xa pair-packed [64kp][128px] half2 during MFMA; [px][co] f16 transpose in epilogue.
__global__ __launch_bounds__(256) void k_gemm1(const float* __restrict__ xg, const float* __restrict__ w,
    const float* __restrict__ bias, __half2* __restrict__ h2tp)
{
  __shared__ f16 wl[128][132];     // 33792 B (stays live across both tiles)
  __shared__ f16 buf[128*132];     // 33792 B (xa / transpose)  -> 67.6KB: 2 blocks/CU
  __half2* xa = (__half2*)buf;
  const int t = threadIdx.x, l = t&63, wid = t>>6;
  const size_t pgB = (size_t)blockIdx.x * 256;
  const int b = (int)(pgB>>16);

  // ---- stage w (16384 f32) ONCE for both tiles ----
  #pragma unroll
  for (int i=0;i<16;++i){
    const int f4 = i*256 + t;
    const int row = f4>>5, col = (f4&31)*4;
    const float4 v = ((const float4*)w)[f4];
    const f16x4 pk = {(f16)v.x,(f16)v.y,(f16)v.z,(f16)v.w};
    *(f16x4*)&wl[row][col] = pk;
  }

  const int px = wid*32 + (l&31);
  const int* xaI = (const int*)xa;

  for (int mt=0; mt<2; ++mt){
    const size_t pg0 = pgB + mt*128;
    const int hw0 = (int)(pg0&65535);
    __syncthreads();   // wl ready (mt=0) / prev epilogue buf reads done (mt=1)

    // ---- stage x full-K pair-packed ----
    #pragma unroll
    for (int i=0;i<8;++i){
      const int u = i*256 + t;
      const int kp = u>>5, px4 = (u&31)*4;
      const float* p0 = xg + (((size_t)(b*128 + 2*kp))<<16) + hw0 + px4;
      const float4 ev = *(const float4*)p0;
      const float4 ov = *(const float4*)(p0 + 65536);
      int4 pk;
      ((__half2*)&pk)[0]=f2h2(ev.x,ov.x); ((__half2*)&pk)[1]=f2h2(ev.y,ov.y);
      ((__half2*)&pk)[2]=f2h2(ev.z,ov.z); ((__half2*)&pk)[3]=f2h2(ev.w,ov.w);
      *(int4*)&xa[kp*128 + px4] = pk;
    }
    __syncthreads();

    f32x16 acc[4];
    #pragma unroll
    for (int nt=0;nt<4;++nt) acc[nt]=zero16();
    #pragma unroll
    for (int kq=0; kq<8; ++kq){
      const int kp0 = kq*8 + (l>>5)*4;
      int4 tmp;
      tmp.x = xaI[(kp0+0)*128 + px];
      tmp.y = xaI[(kp0+1)*128 + px];
      tmp.z = xaI[(kp0+2)*128 + px];
      tmp.w = xaI[(kp0+3)*128 + px];
      const f16x8 A = __builtin_bit_cast(f16x8, tmp);
      #pragma unroll
      for (int nt=0; nt<4; ++nt){
        const f16x8 Bf = *(const f16x8*)&wl[nt*32 + (l&31)][kq*16 + (l>>5)*8];
        acc[nt] = __builtin_amdgcn_mfma_f32_32x32x16_f16(A, Bf, acc[nt], 0,0,0);
      }
    }
    __syncthreads();   // xa reads done; buf becomes transpose tile

    // ---- epilogue: gelu -> buf transpose ([px][co], stride 132) -> planar stores ----
    #pragma unroll
    for (int nt=0;nt<4;++nt){
      const int co = nt*32 + (l&31);
      const float bi = bias[co];
      #pragma unroll
      for (int r=0;r<16;++r){
        const int p = wid*32 + (r&3) + 8*(r>>2) + 4*(l>>5);
        buf[p*132 + co] = (f16)gelu(acc[nt][r] + bi);
      }
    }
    __syncthreads();
    #pragma unroll
    for (int i=0;i<32;++i){
      const int idx = i*256 + t;
      const int cp = idx>>7, pp = idx&127;
      h2tp[(size_t)cp*262144 + pg0 + pp] = *(const __half2*)&buf[pp*132 + 2*cp];
    }
  }
}

// ---------------- FFTW2 (fused rfft-W + T1): planar h -> buf2 [n][wf][i][H] + nyq ----------------
__global__ __launch_bounds__(256) void k_fftw(const __half2* __restrict__ h2tp,
    __half2* __restrict__ buf2, __half2* __restrict__ nyq)
{
  __shared__ __half2 fb[32*256];
  const int t = threadIdx.x;
  const int htl = blockIdx.x, cp = blockIdx.y, b = blockIdx.z;
  const int h0 = htl<<5;
  const int n = cp>>3, ii0 = (cp&7)*2;
  const size_t src = (size_t)cp*262144 + (size_t)b*65536 + (size_t)h0*256;

  #pragma unroll
  for (int i=0;i<8;++i){
    const int idx = i*256 + t;
    const int hr = idx>>6, w4 = (idx&63)*4;
    const float4 v = *(const float4*)(h2tp + src + hr*256 + w4);
    const __half2* vp = (const __half2*)&v;
    #pragma unroll
    for (int j=0;j<4;++j) fb[swzF(hr*256 + w4 + j)] = vp[j];
  }
  __syncthreads();

  fft256<-1,1>(fb, 32, t, 256);

  const int hr = t&31, cg = t>>5;
  const size_t obase = (size_t)(b*8+n)*128*16*256;
  #pragma unroll
  for (int it=0; it<32; ++it){
    const int c = it*8 + cg;
    const int k = c>>1, chb = c&1;
    const float2 zk = h2f2(fb[swzF(hr*256 + rev4(k))]);
    const float2 zm = h2f2(fb[swzF(hr*256 + rev4((256-k)&255))]);
    float2 o;
    if (chb==0) o = make_float2((zk.x+zm.x)*0.03125f, (zk.y-zm.y)*0.03125f);
    else        o = make_float2((zk.y+zm.y)*0.03125f, (zm.x-zk.x)*0.03125f);
    buf2[obase + ((size_t)k*16 + ii0+chb)*256 + h0 + hr] = f2h2(o.x, o.y);
  }
  if (t < 64){
    const int chb = t>>5, hq = t&31;
    const float2 zk = h2f2(fb[swzF(hq*256 + rev4(128))]);
    const float v = (chb==0 ? zk.x : zk.y)*0.0625f;
    nyq[((size_t)(b*8+n)*16 + ii0+chb)*256 + h0 + hq] = f2h2(v, 0.f);
  }
}

// ---------------- spec body: FFT along H + complex block-MLP (MFMA) + inverse ----------------
DEVI void spec_body(__half2* data, __half2* xp, __half2* o1b, int n,
                    const float* __restrict__ w1, const float* __restrict__ b1,
                    const float* __restrict__ w2, const float* __restrict__ b2, int t)
{
  fft256<-1,0>(data, 16, t, 256);

  const int l = t&63, wid = t>>6;
  const int o = l&15, kb = l>>4;

  f16x8 B1R, B1I, B2R, B2I;
  #pragma unroll
  for (int j=0;j<8;++j){
    const int i = kb*4 + (j>>1);
    const float a1r = w1[(n*16+i)*16+o], a1i = w1[2048 + (n*16+i)*16+o];
    const float a2r = w2[(n*16+i)*16+o], a2i = w2[2048 + (n*16+i)*16+o];
    B1R[j] = (f16)(((j&1) ? -a1i : a1r) * 0.0625f);
    B1I[j] = (f16)(((j&1) ?  a1r : a1i) * 0.0625f);
    B2R[j] = (f16)((j&1) ? -a2i : a2r);
    B2I[j] = (f16)((j&1) ?  a2r : a2i);
  }
  const float b1r = b1[n*16+o],     b1i = b1[128 + n*16+o];
  const float b2r = b2[n*16+o],     b2i = b2[128 + n*16+o];
  const f32x4 cR1 = {b1r,b1r,b1r,b1r}, cI1 = {b1i,b1i,b1i,b1i};
  const f32x4 cR2 = {b2r,b2r,b2r,b2r}, cI2 = {b2i,b2i,b2i,b2i};

  #pragma unroll
  for (int i=0;i<16;++i) xp[t*17 + i] = data[(i<<8) + t];
  __syncthreads();

  const int* xpI  = (const int*)xp;
  const int* o1bI = (const int*)o1b;
  __half2*  ob    = o1b + wid*(16*17);

  #pragma unroll
  for (int tt=0; tt<4; ++tt){
    const int p0 = wid*64 + tt*16;
    f16x8 A1;
    { int4 tmp;
      const int ab = (p0 + o)*17 + kb*4;
      tmp.x=xpI[ab]; tmp.y=xpI[ab+1]; tmp.z=xpI[ab+2]; tmp.w=xpI[ab+3];
      A1 = __builtin_bit_cast(f16x8, tmp); }
    f32x4 aR = __builtin_amdgcn_mfma_f32_16x16x32_f16(A1, B1R, cR1, 0,0,0);
    f32x4 aI = __builtin_amdgcn_mfma_f32_16x16x32_f16(A1, B1I, cI1, 0,0,0);
    #pragma unroll
    for (int r=0;r<4;++r)
      ob[(kb*4+r)*17 + o] = f2h2(fmaxf(aR[r],0.f), fmaxf(aI[r],0.f));
    f16x8 A2;
    { int4 tmp;
      const int ab = wid*(16*17) + o*17 + kb*4;
      tmp.x=o1bI[ab]; tmp.y=o1bI[ab+1]; tmp.z=o1bI[ab+2]; tmp.w=o1bI[ab+3];
      A2 = __builtin_bit_cast(f16x8, tmp); }
    f32x4 oR = __builtin_amdgcn_mfma_f32_16x16x32_f16(A2, B2R, cR2, 0,0,0);
    f32x4 oI = __builtin_amdgcn_mfma_f32_16x16x32_f16(A2, B2I, cI2, 0,0,0);
    #pragma unroll
    for (int r=0;r<4;++r)
      xp[(p0 + kb*4 + r)*17 + o] = f2h2(sshrink(oR[r]), sshrink(oI[r]));
  }
  __syncthreads();

  #pragma unroll
  for (int i=0;i<16;++i) data[(i<<8) + t] = xp[t*17 + i];
  __syncthreads();

  fft256<1,0>(data, 16, t, 256);
}

// grid (128, 8, 4): wf<128 from buf2 (float4 I/O, unswizzled)
__global__ __launch_bounds__(256) void k_spec(__half2* __restrict__ buf2,
    const float* __restrict__ w1, const float* __restrict__ b1,
    const float* __restrict__ w2, const float* __restrict__ b2)
{
  __shared__ __half2 data[16*256];
  __shared__ __half2 xp[256*17];
  __shared__ __half2 o1b[4*16*17];
  const int t = threadIdx.x;
  const int wf = blockIdx.x, n = blockIdx.y, b = blockIdx.z;
  __half2* chunk = buf2 + ((size_t)((b*8 + n)*128 + wf) << 12);
  #pragma unroll
  for (int p=0; p<4; ++p) ((float4*)data)[(p<<8)+t] = ((const float4*)chunk)[(p<<8)+t];
  __syncthreads();
  spec_body(data, xp, o1b, n, w1,b1,w2,b2, t);
  #pragma unroll
  for (int p=0; p<4; ++p) ((float4*)chunk)[(p<<8)+t] = ((const float4*)data)[(p<<8)+t];
}

// grid (8, 4): wf==128 from dense nyq plane
__global__ __launch_bounds__(256) void k_spec_nyq(__half2* __restrict__ nyq,
    const float* __restrict__ w1, const float* __restrict__ b1,
    const float* __restrict__ w2, const float* __restrict__ b2)
{
  __shared__ __half2 data[16*256];
  __shared__ __half2 xp[256*17];
  __shared__ __half2 o1b[4*16*17];
  const int t = threadIdx.x;
  const int n = blockIdx.x, b = blockIdx.y;
  const size_t nbase = (size_t)(b*8+n)*16*256;
  #pragma unroll
  for (int i=0;i<16;++i)
    data[(i<<8) + t] = nyq[nbase + i*256 + t];
  __syncthreads();
  spec_body(data, xp, o1b, n, w1,b1,w2,b2, t);
  #pragma unroll
  for (int i=0;i<16;++i)
    nyq[nbase + i*256 + t] = data[(i<<8) + t];
}

// ---------------- IFFTW2 (fused T2 + irfft-W + s): buf2+nyq -> stp planar ----------------
__global__ __launch_bounds__(256) void k_ifftw(const __half2* __restrict__ buf2,
    const __half2* __restrict__ nyq, const __half2* __restrict__ h2tp,
    __half2* __restrict__ stp)
{
  __shared__ __half2 fb[32*256];
  const int t = threadIdx.x;
  const int htl = blockIdx.x, cp = blockIdx.y, b = blockIdx.z;
  const int h0 = htl<<5;
  const int n = cp>>3, ii0 = (cp&7)*2;
  const int hr = t&31, cg = t>>5;
  const size_t ibase = (size_t)(b*8+n)*128*16*256;
  const size_t nbase = (size_t)(b*8+n)*16*256;

  #pragma unroll
  for (int it=0; it<32; ++it){
    const int k = it*8 + cg;
    const int kk = (k<=128) ? k : 256-k;
    float2 va, vb;
    if (kk==128){
      va = h2f2(nyq[nbase + (size_t)(ii0  )*256 + h0+hr]);
      vb = h2f2(nyq[nbase + (size_t)(ii0+1)*256 + h0+hr]);
    } else {
      va = h2f2(buf2[ibase + ((size_t)kk*16 + ii0  )*256 + h0+hr]);
      vb = h2f2(buf2[ibase + ((size_t)kk*16 + ii0+1)*256 + h0+hr]);
    }
    float2 Z = (k<=128) ? make_float2(va.x - vb.y, va.y + vb.x)
                        : make_float2(va.x + vb.y, vb.x - va.y);
    if (k==0 || k==128) Z = make_float2(va.x, vb.x);
    fb[swzF(hr*256 + rev4(k))] = f2h2(Z.x, Z.y);
  }
  __syncthreads();

  fft256<1,1>(fb, 32, t, 256);   // y (unnormalized: 256x ortho)

  const size_t pbase = (size_t)cp*262144 + (size_t)b*65536 + (size_t)h0*256;
  #pragma unroll
  for (int i=0;i<8;++i){
    const int idx = i*256 + t;
    const int h2 = idx>>6, w4 = (idx&63)*4;
    const float4 hv4 = *(const float4*)(h2tp + pbase + h2*256 + w4);
    const __half2* hv = (const __half2*)&hv4;
    float4 out4; __half2* ov = (__half2*)&out4;
    #pragma unroll
    for (int j=0;j<4;++j){
      const float2 y = h2f2(fb[swzF(h2*256 + w4 + j)]);
      const float2 hh = h2f2(hv[j]);
      ov[j] = f2h2(hh.x + y.x*0.00390625f, hh.y + y.y*0.00390625f);
    }
    *(float4*)(stp + pbase + h2*256 + w4) = out4;
  }
}

// ---------------- GEMM2 (planar s staging, full-K, x prefetch): out = p2.s + p2b + x ----------------
__global__ __launch_bounds__(256) void k_gemm2(const __half2* __restrict__ stp, const float* __restrict__ w,
    const float* __restrict__ bias, const float* __restrict__ xg, float* __restrict__ outg)
{
  __shared__ __half2 sl[64*128];   // 32KB
  __shared__ f16 wl[128][132];     // 33KB
  __shared__ float bB[128];
  const int t = threadIdx.x, l = t&63, wid = t>>6;
  const int col = l&31;
  const size_t pg0 = (size_t)blockIdx.x * 128;
  const int b = (int)(pg0>>16), hw0 = (int)(pg0 & 65535);

  #pragma unroll
  for (int i=0;i<16;++i){
    const int f4 = i*256 + t;
    const int row = f4>>5, c4 = (f4&31)*4;
    const float4 v = ((const float4*)w)[f4];
    const f16x4 pk = {(f16)v.x,(f16)v.y,(f16)v.z,(f16)v.w};
    *(f16x4*)&wl[row][c4] = pk;
  }
  #pragma unroll
  for (int i=0;i<8;++i){
    const int idx = i*256 + t;
    const int cp = idx>>5, px4 = (idx&31)*4;
    *(float4*)&sl[cp*128 + px4] = *(const float4*)(stp + (size_t)cp*262144 + pg0 + px4);
  }
  if (t < 128) bB[t] = bias[t];
  __syncthreads();

  const int orow = wid*32 + 4*(l>>5);
  float xv[64];
  #pragma unroll
  for (int nt=0;nt<4;++nt){
    #pragma unroll
    for (int r=0;r<16;++r){
      const int o = orow + (r&3) + 8*(r>>2);
      xv[nt*16+r] = xg[(((size_t)(b*128+o))<<16) + (size_t)(hw0 + nt*32 + col)];
    }
  }

  const int* slI = (const int*)sl;
  f32x16 acc0=zero16(), acc1=zero16(), acc2=zero16(), acc3=zero16();
  #pragma unroll
  for (int c=0;c<8;++c){
    const int ko = c*16 + (l>>5)*8;
    const int kq = ko>>1;
    const f16x8 a = *(const f16x8*)&wl[wid*32+col][ko];
    auto mkB = [&](int pxb){
      int4 tmp;
      tmp.x = slI[(kq+0)*128 + pxb+col];
      tmp.y = slI[(kq+1)*128 + pxb+col];
      tmp.z = slI[(kq+2)*128 + pxb+col];
      tmp.w = slI[(kq+3)*128 + pxb+col];
      return __builtin_bit_cast(f16x8, tmp);
    };
    acc0 = __builtin_amdgcn_mfma_f32_32x32x16_f16(a, mkB(0),  acc0, 0,0,0);
    acc1 = __builtin_amdgcn_mfma_f32_32x32x16_f16(a, mkB(32), acc1, 0,0,0);
    acc2 = __builtin_amdgcn_mfma_f32_32x32x16_f16(a, mkB(64), acc2, 0,0,0);
    acc3 = __builtin_amdgcn_mfma_f32_32x32x16_f16(a, mkB(96), acc3, 0,0,0);
  }

  auto store2 = [&](const f32x16& A, int nt){
    #pragma unroll
    for (int r=0;r<16;++r){
      const int o = orow + (r&3) + 8*(r>>2);
      const size_t addr = (((size_t)(b*128+o))<<16) + (size_t)(hw0 + nt*32 + col);
      outg[addr] = A[r] + bB[o] + xv[nt*16+r];
    }
  };
  store2(acc0,0); store2(acc1,1); store2(acc2,2); store2(acc3,3);
}

extern "C" void kernel_launch(void* const* d_in, const int* in_sizes, int n_in,
                              void* d_out, int out_size, void* d_ws, size_t ws_size,
                              hipStream_t stream)
{
  (void)in_sizes; (void)n_in; (void)out_size; (void)ws_size;
  const float* x   = (const float*)d_in[0];
  const float* p1w = (const float*)d_in[1];
  const float* p1b = (const float*)d_in[2];
  const float* w1  = (const float*)d_in[3];
  const float* b1  = (const float*)d_in[4];
  const float* w2  = (const float*)d_in[5];
  const float* b2  = (const float*)d_in[6];
  const float* p2w = (const float*)d_in[7];
  const float* p2b = (const float*)d_in[8];
  float* out = (float*)d_out;

  const size_t ST_B = 262144UL*128*2;   // 67,108,864
  // d_out: buf2 [0,67.1M) | h2tp planar [67.1M,134.2M)  (both dead before gemm2 writes)
  // ws   : stp planar [0,67.1M) | nyq plane [67.1M,67.6M)
  __half2* buf2 = (__half2*)d_out;
  __half2* h2tp = (__half2*)((char*)d_out + ST_B);
  __half2* stp  = (__half2*)d_ws;
  __half2* nyq  = (__half2*)((char*)d_ws + ST_B);

  k_gemm1   <<<dim3(1024),     dim3(256), 0, stream>>>(x, p1w, p1b, h2tp);
  k_fftw    <<<dim3(8,64,4),   dim3(256), 0, stream>>>(h2tp, buf2, nyq);
  k_spec    <<<dim3(128,8,4),  dim3(256), 0, stream>>>(buf2, w1, b1, w2, b2);
  k_spec_nyq<<<dim3(8,4),      dim3(256), 0, stream>>>(nyq, w1, b1, w2, b2);
  k_ifftw   <<<dim3(8,64,4),   dim3(256), 0, stream>>>(buf2, nyq, h2tp, stp);
  k_gemm2   <<<dim3(2048),     dim3(256), 0, stream>>>(stp, p2w, p2b, x, out);
}

// Round 19
// 262.529 us; speedup vs baseline: 1.0451x; 1.0451x over previous
//
#include <hip/hip_runtime.h>
#include <hip/hip_fp16.h>

#define DEVI __device__ __forceinline__

typedef _Float16 f16;
typedef _Float16 f16x8 __attribute__((ext_vector_type(8)));
typedef _Float16 f16x4 __attribute__((ext_vector_type(4)));
typedef float    f32x4  __attribute__((ext_vector_type(4)));
typedef float    f32x16 __attribute__((ext_vector_type(16)));

DEVI float2 cmul(float2 a, float2 b){ return make_float2(fmaf(a.x,b.x,-(a.y*b.y)), fmaf(a.x,b.y,a.y*b.x)); }
DEVI float2 h2f2(__half2 v){ return make_float2(__low2float(v), __high2float(v)); }
DEVI __half2 f2h2(float a, float b){ return __floats2half2_rn(a, b); }
DEVI __half2 hswap(__half2 v){ __half2 r; r.x = v.y; r.y = v.x; return r; }
DEVI int rev4(int k){ return ((k&3)<<6) | (((k>>2)&3)<<4) | (((k>>4)&3)<<2) | ((k>>6)&3); }
// tanh-form GELU (max err ~3e-3). inf-safe via __expf.
DEVI float gelu(float v){
  const float u2 = 1.5957691216057308f*v*(1.0f + 0.044715f*v*v);
  const float e = __expf(u2);
  return v - v/(e + 1.0f);
}
DEVI float sshrink(float v){ return v > 0.01f ? v-0.01f : (v < -0.01f ? v+0.01f : 0.0f); }
// swzF: word-granule fold (x5 spreads bits[7:5] into [2:0]&[4:2]) + row-fold; W-FFT kernels only.
DEVI int swzF(int a){ return a ^ ((5*((a>>5)&7))&31) ^ ((a>>8)&31); }
DEVI f32x16 zero16(){
  f32x16 z;
#pragma unroll
  for (int i=0;i<16;++i) z[i]=0.f;
  return z;
}

// packed complex multiply by twiddle (c,d): re = x c - y d ; im = y c + x d
// cc = {c,c}, dd = {-d, +d}
DEVI __half2 cmulp(__half2 v, __half2 cc, __half2 dd){
  return __hfma2(v, cc, __hmul2(hswap(v), dd));
}

// In-place FFT over `rows` rows of 256 complex values (half2 in LDS, PACKED f16 math).
// DIR=-1: forward DIF (natural -> base-4 digit-reversed).
// DIR=+1: inverse DIT (digit-reversed -> natural, UNNORMALIZED).
// SW: 0 = none, 1 = swzF. Twiddles hoisted (lane-constant per stage), f32-generated.
template<int DIR, int SW>
DEVI void fft256(__half2* d, int rows, int tid, int nthr){
  const int w   = tid & 63;
  const int r0  = tid >> 6;
  const int rst = nthr >> 6;
  const __half2 NI = f2h2( 1.f,-1.f);   // mul by -i after swap
  const __half2 PI_= f2h2(-1.f, 1.f);   // mul by +i after swap
  #pragma unroll
  for (int si=0; si<4; ++si){
    const int lq = (DIR<0) ? (6-2*si) : (2*si);
    const int q4 = 1<<lq;
    const int j = w & (q4-1);
    const int blk = w >> lq;
    const int aoff = (blk<<(lq+2)) + j;
    const int e = j*(64>>lq);
    float sn, cs;
    __sincosf((float)(DIR*e) * 0.0245436926061703f, &sn, &cs);
    const float cs2 = cs*cs - sn*sn, sn2 = 2.f*cs*sn;
    const float cs3 = cs2*cs - sn2*sn, sn3 = sn2*cs + cs2*sn;
    const __half2 cc1 = f2h2(cs,cs),   dd1 = f2h2(-sn,sn);
    const __half2 cc2 = f2h2(cs2,cs2), dd2 = f2h2(-sn2,sn2);
    const __half2 cc3 = f2h2(cs3,cs3), dd3 = f2h2(-sn3,sn3);
    for (int r = r0; r < rows; r += rst){
      const int base = (r<<8) + aoff;
      const int a0 = SW ? swzF(base)        : base;
      const int a1 = SW ? swzF(base+q4)     : base+q4;
      const int a2 = SW ? swzF(base+2*q4)   : base+2*q4;
      const int a3 = SW ? swzF(base+3*q4)   : base+3*q4;
      if (DIR < 0){
        const __half2 x0=d[a0], x1=d[a1], x2=d[a2], x3=d[a3];
        const __half2 t0=__hadd2(x0,x2), t1=__hsub2(x0,x2), t2=__hadd2(x1,x3);
        const __half2 t3=__hmul2(hswap(__hsub2(x1,x3)), NI);
        d[a0] = __hadd2(t0,t2);
        d[a1] = cmulp(__hadd2(t1,t3), cc1, dd1);
        d[a2] = cmulp(__hsub2(t0,t2), cc2, dd2);
        d[a3] = cmulp(__hsub2(t1,t3), cc3, dd3);
      } else {
        const __half2 x0 = d[a0];
        const __half2 b1 = cmulp(d[a1], cc1, dd1);
        const __half2 b2 = cmulp(d[a2], cc2, dd2);
        const __half2 b3 = cmulp(d[a3], cc3, dd3);
        const __half2 t0=__hadd2(x0,b2), t1=__hsub2(x0,b2), t2=__hadd2(b1,b3);
        const __half2 t3=__hmul2(hswap(__hsub2(b1,b3)), PI_);
        d[a0] = __hadd2(t0,t2);
        d[a1] = __hadd2(t1,t3);
        d[a2] = __hsub2(t0,t2);
        d[a3] = __hsub2(t1,t3);
      }
    }
    __syncthreads();
  }
}

// ---------------- GEMM1 v5 (full-K single-stage, pair-packed): h planar = gelu(p1w.x + p1b) ----------------
__global__ __launch_bounds__(256) void k_gemm1(const float* __restrict__ xg, const float* __restrict__ w,
    const float* __restrict__ bias, __half2* __restrict__ h2tp)
{
  __shared__ f16 wl[128][132];     // 33792 B
  __shared__ __half2 xa[64*128];   // 32768 B
  const int t = threadIdx.x, l = t&63, wid = t>>6;
  const size_t pg0 = (size_t)blockIdx.x * 128;
  const int b = (int)(pg0>>16), hw0 = (int)(pg0&65535);

  #pragma unroll
  for (int i=0;i<16;++i){
    const int f4 = i*256 + t;
    const int row = f4>>5, col = (f4&31)*4;
    const float4 v = ((const float4*)w)[f4];
    const f16x4 pk = {(f16)v.x,(f16)v.y,(f16)v.z,(f16)v.w};
    *(f16x4*)&wl[row][col] = pk;
  }
  #pragma unroll
  for (int i=0;i<8;++i){
    const int u = i*256 + t;
    const int kp = u>>5, px4 = (u&31)*4;
    const float* p0 = xg + (((size_t)(b*128 + 2*kp))<<16) + hw0 + px4;
    const float4 ev = *(const float4*)p0;
    const float4 ov = *(const float4*)(p0 + 65536);
    int4 pk;
    ((__half2*)&pk)[0]=f2h2(ev.x,ov.x); ((__half2*)&pk)[1]=f2h2(ev.y,ov.y);
    ((__half2*)&pk)[2]=f2h2(ev.z,ov.z); ((__half2*)&pk)[3]=f2h2(ev.w,ov.w);
    *(int4*)&xa[kp*128 + px4] = pk;
  }
  __syncthreads();

  const int px = wid*32 + (l&31);
  const int* xaI = (const int*)xa;
  f32x16 acc[4];
  #pragma unroll
  for (int nt=0;nt<4;++nt) acc[nt]=zero16();

  #pragma unroll
  for (int kq=0; kq<8; ++kq){
    const int kp0 = kq*8 + (l>>5)*4;
    int4 tmp;
    tmp.x = xaI[(kp0+0)*128 + px];
    tmp.y = xaI[(kp0+1)*128 + px];
    tmp.z = xaI[(kp0+2)*128 + px];
    tmp.w = xaI[(kp0+3)*128 + px];
    const f16x8 A = __builtin_bit_cast(f16x8, tmp);
    #pragma unroll
    for (int nt=0; nt<4; ++nt){
      const f16x8 Bf = *(const f16x8*)&wl[nt*32 + (l&31)][kq*16 + (l>>5)*8];
      acc[nt] = __builtin_amdgcn_mfma_f32_32x32x16_f16(A, Bf, acc[nt], 0,0,0);
    }
  }

  __syncthreads();
  f16* wlT = &wl[0][0];
  #pragma unroll
  for (int nt=0;nt<4;++nt){
    const int co = nt*32 + (l&31);
    const float bi = bias[co];
    #pragma unroll
    for (int r=0;r<16;++r){
      const int p = wid*32 + (r&3) + 8*(r>>2) + 4*(l>>5);
      wlT[p*132 + co] = (f16)gelu(acc[nt][r] + bi);
    }
  }
  __syncthreads();
  #pragma unroll
  for (int i=0;i<32;++i){
    const int idx = i*256 + t;
    const int cp = idx>>7, pp = idx&127;
    h2tp[(size_t)cp*262144 + pg0 + pp] = *(const __half2*)&wlT[pp*132 + 2*cp];
  }
}

// ---------------- FFTW2 (fused rfft-W + T1): planar h -> buf2 [n][wf][i][H] + nyq ----------------
__global__ __launch_bounds__(256) void k_fftw(const __half2* __restrict__ h2tp,
    __half2* __restrict__ buf2, __half2* __restrict__ nyq)
{
  __shared__ __half2 fb[32*256];
  const int t = threadIdx.x;
  const int htl = blockIdx.x, cp = blockIdx.y, b = blockIdx.z;
  const int h0 = htl<<5;
  const int n = cp>>3, ii0 = (cp&7)*2;
  const size_t src = (size_t)cp*262144 + (size_t)b*65536 + (size_t)h0*256;

  #pragma unroll
  for (int i=0;i<8;++i){
    const int idx = i*256 + t;
    const int hr = idx>>6, w4 = (idx&63)*4;
    const float4 v = *(const float4*)(h2tp + src + hr*256 + w4);
    const __half2* vp = (const __half2*)&v;
    #pragma unroll
    for (int j=0;j<4;++j) fb[swzF(hr*256 + w4 + j)] = vp[j];
  }
  __syncthreads();

  fft256<-1,1>(fb, 32, t, 256);

  const int hr = t&31, cg = t>>5;
  const size_t obase = (size_t)(b*8+n)*128*16*256;
  #pragma unroll
  for (int it=0; it<32; ++it){
    const int c = it*8 + cg;
    const int k = c>>1, chb = c&1;
    const float2 zk = h2f2(fb[swzF(hr*256 + rev4(k))]);
    const float2 zm = h2f2(fb[swzF(hr*256 + rev4((256-k)&255))]);
    float2 o;
    if (chb==0) o = make_float2((zk.x+zm.x)*0.03125f, (zk.y-zm.y)*0.03125f);
    else        o = make_float2((zk.y+zm.y)*0.03125f, (zm.x-zk.x)*0.03125f);
    buf2[obase + ((size_t)k*16 + ii0+chb)*256 + h0 + hr] = f2h2(o.x, o.y);
  }
  if (t < 64){
    const int chb = t>>5, hq = t&31;
    const float2 zk = h2f2(fb[swzF(hq*256 + rev4(128))]);
    const float v = (chb==0 ? zk.x : zk.y)*0.0625f;
    nyq[((size_t)(b*8+n)*16 + ii0+chb)*256 + h0 + hq] = f2h2(v, 0.f);
  }
}

// ---------------- spec body: FFT along H + complex block-MLP (MFMA) + inverse ----------------
DEVI void spec_body(__half2* data, __half2* xp, __half2* o1b, int n,
                    const float* __restrict__ w1, const float* __restrict__ b1,
                    const float* __restrict__ w2, const float* __restrict__ b2, int t)
{
  fft256<-1,0>(data, 16, t, 256);

  const int l = t&63, wid = t>>6;
  const int o = l&15, kb = l>>4;

  f16x8 B1R, B1I, B2R, B2I;
  #pragma unroll
  for (int j=0;j<8;++j){
    const int i = kb*4 + (j>>1);
    const float a1r = w1[(n*16+i)*16+o], a1i = w1[2048 + (n*16+i)*16+o];
    const float a2r = w2[(n*16+i)*16+o], a2i = w2[2048 + (n*16+i)*16+o];
    B1R[j] = (f16)(((j&1) ? -a1i : a1r) * 0.0625f);
    B1I[j] = (f16)(((j&1) ?  a1r : a1i) * 0.0625f);
    B2R[j] = (f16)((j&1) ? -a2i : a2r);
    B2I[j] = (f16)((j&1) ?  a2r : a2i);
  }
  const float b1r = b1[n*16+o],     b1i = b1[128 + n*16+o];
  const float b2r = b2[n*16+o],     b2i = b2[128 + n*16+o];
  const f32x4 cR1 = {b1r,b1r,b1r,b1r}, cI1 = {b1i,b1i,b1i,b1i};
  const f32x4 cR2 = {b2r,b2r,b2r,b2r}, cI2 = {b2i,b2i,b2i,b2i};

  #pragma unroll
  for (int i=0;i<16;++i) xp[t*17 + i] = data[(i<<8) + t];
  __syncthreads();

  const int* xpI  = (const int*)xp;
  const int* o1bI = (const int*)o1b;
  __half2*  ob    = o1b + wid*(16*17);

  #pragma unroll
  for (int tt=0; tt<4; ++tt){
    const int p0 = wid*64 + tt*16;
    f16x8 A1;
    { int4 tmp;
      const int ab = (p0 + o)*17 + kb*4;
      tmp.x=xpI[ab]; tmp.y=xpI[ab+1]; tmp.z=xpI[ab+2]; tmp.w=xpI[ab+3];
      A1 = __builtin_bit_cast(f16x8, tmp); }
    f32x4 aR = __builtin_amdgcn_mfma_f32_16x16x32_f16(A1, B1R, cR1, 0,0,0);
    f32x4 aI = __builtin_amdgcn_mfma_f32_16x16x32_f16(A1, B1I, cI1, 0,0,0);
    #pragma unroll
    for (int r=0;r<4;++r)
      ob[(kb*4+r)*17 + o] = f2h2(fmaxf(aR[r],0.f), fmaxf(aI[r],0.f));
    f16x8 A2;
    { int4 tmp;
      const int ab = wid*(16*17) + o*17 + kb*4;
      tmp.x=o1bI[ab]; tmp.y=o1bI[ab+1]; tmp.z=o1bI[ab+2]; tmp.w=o1bI[ab+3];
      A2 = __builtin_bit_cast(f16x8, tmp); }
    f32x4 oR = __builtin_amdgcn_mfma_f32_16x16x32_f16(A2, B2R, cR2, 0,0,0);
    f32x4 oI = __builtin_amdgcn_mfma_f32_16x16x32_f16(A2, B2I, cI2, 0,0,0);
    #pragma unroll
    for (int r=0;r<4;++r)
      xp[(p0 + kb*4 + r)*17 + o] = f2h2(sshrink(oR[r]), sshrink(oI[r]));
  }
  __syncthreads();

  #pragma unroll
  for (int i=0;i<16;++i) data[(i<<8) + t] = xp[t*17 + i];
  __syncthreads();

  fft256<1,0>(data, 16, t, 256);
}

// grid (129, 8, 4): wf<128 from buf2 (float4 I/O); wf==128 from dense nyq plane.
__global__ __launch_bounds__(256) void k_spec(__half2* __restrict__ buf2, __half2* __restrict__ nyq,
    const float* __restrict__ w1, const float* __restrict__ b1,
    const float* __restrict__ w2, const float* __restrict__ b2)
{
  __shared__ __half2 data[16*256];
  __shared__ __half2 xp[256*17];
  __shared__ __half2 o1b[4*16*17];
  const int t = threadIdx.x;
  const int wf = blockIdx.x, n = blockIdx.y, b = blockIdx.z;
  __half2* chunk = buf2 + ((size_t)((b*8 + n)*128 + wf) << 12);
  const size_t nbase = (size_t)(b*8+n)*16*256;
  if (wf < 128){
    #pragma unroll
    for (int p=0; p<4; ++p) ((float4*)data)[(p<<8)+t] = ((const float4*)chunk)[(p<<8)+t];
  } else {
    #pragma unroll
    for (int i=0;i<16;++i) data[(i<<8) + t] = nyq[nbase + i*256 + t];
  }
  __syncthreads();
  spec_body(data, xp, o1b, n, w1,b1,w2,b2, t);
  if (wf < 128){
    #pragma unroll
    for (int p=0; p<4; ++p) ((float4*)chunk)[(p<<8)+t] = ((const float4*)data)[(p<<8)+t];
  } else {
    #pragma unroll
    for (int i=0;i<16;++i) nyq[nbase + i*256 + t] = data[(i<<8) + t];
  }
}

// ---------------- IFFTW2 (fused T2 + irfft-W + s): buf2+nyq -> stp planar ----------------
__global__ __launch_bounds__(256) void k_ifftw(const __half2* __restrict__ buf2,
    const __half2* __restrict__ nyq, const __half2* __restrict__ h2tp,
    __half2* __restrict__ stp)
{
  __shared__ __half2 fb[32*256];
  const int t = threadIdx.x;
  const int htl = blockIdx.x, cp = blockIdx.y, b = blockIdx.z;
  const int h0 = htl<<5;
  const int n = cp>>3, ii0 = (cp&7)*2;
  const int hr = t&31, cg = t>>5;
  const size_t ibase = (size_t)(b*8+n)*128*16*256;
  const size_t nbase = (size_t)(b*8+n)*16*256;

  #pragma unroll
  for (int it=0; it<32; ++it){
    const int k = it*8 + cg;
    const int kk = (k<=128) ? k : 256-k;
    float2 va, vb;
    if (kk==128){
      va = h2f2(nyq[nbase + (size_t)(ii0  )*256 + h0+hr]);
      vb = h2f2(nyq[nbase + (size_t)(ii0+1)*256 + h0+hr]);
    } else {
      va = h2f2(buf2[ibase + ((size_t)kk*16 + ii0  )*256 + h0+hr]);
      vb = h2f2(buf2[ibase + ((size_t)kk*16 + ii0+1)*256 + h0+hr]);
    }
    float2 Z = (k<=128) ? make_float2(va.x - vb.y, va.y + vb.x)
                        : make_float2(va.x + vb.y, vb.x - va.y);
    if (k==0 || k==128) Z = make_float2(va.x, vb.x);
    fb[swzF(hr*256 + rev4(k))] = f2h2(Z.x, Z.y);
  }
  __syncthreads();

  fft256<1,1>(fb, 32, t, 256);   // y (unnormalized: 256x ortho)

  const size_t pbase = (size_t)cp*262144 + (size_t)b*65536 + (size_t)h0*256;
  #pragma unroll
  for (int i=0;i<8;++i){
    const int idx = i*256 + t;
    const int h2 = idx>>6, w4 = (idx&63)*4;
    const float4 hv4 = *(const float4*)(h2tp + pbase + h2*256 + w4);
    const __half2* hv = (const __half2*)&hv4;
    float4 out4; __half2* ov = (__half2*)&out4;
    #pragma unroll
    for (int j=0;j<4;++j){
      const float2 y = h2f2(fb[swzF(h2*256 + w4 + j)]);
      const float2 hh = h2f2(hv[j]);
      ov[j] = f2h2(hh.x + y.x*0.00390625f, hh.y + y.y*0.00390625f);
    }
    *(float4*)(stp + pbase + h2*256 + w4) = out4;
  }
}

// ---------------- GEMM2 (planar s staging, full-K, x prefetch): out = p2.s + p2b + x ----------------
__global__ __launch_bounds__(256) void k_gemm2(const __half2* __restrict__ stp, const float* __restrict__ w,
    const float* __restrict__ bias, const float* __restrict__ xg, float* __restrict__ outg)
{
  __shared__ __half2 sl[64*128];   // 32KB
  __shared__ f16 wl[128][132];     // 33KB
  __shared__ float bB[128];
  const int t = threadIdx.x, l = t&63, wid = t>>6;
  const int col = l&31;
  const size_t pg0 = (size_t)blockIdx.x * 128;
  const int b = (int)(pg0>>16), hw0 = (int)(pg0 & 65535);

  #pragma unroll
  for (int i=0;i<16;++i){
    const int f4 = i*256 + t;
    const int row = f4>>5, c4 = (f4&31)*4;
    const float4 v = ((const float4*)w)[f4];
    const f16x4 pk = {(f16)v.x,(f16)v.y,(f16)v.z,(f16)v.w};
    *(f16x4*)&wl[row][c4] = pk;
  }
  #pragma unroll
  for (int i=0;i<8;++i){
    const int idx = i*256 + t;
    const int cp = idx>>5, px4 = (idx&31)*4;
    *(float4*)&sl[cp*128 + px4] = *(const float4*)(stp + (size_t)cp*262144 + pg0 + px4);
  }
  if (t < 128) bB[t] = bias[t];
  __syncthreads();

  const int orow = wid*32 + 4*(l>>5);
  float xv[64];
  #pragma unroll
  for (int nt=0;nt<4;++nt){
    #pragma unroll
    for (int r=0;r<16;++r){
      const int o = orow + (r&3) + 8*(r>>2);
      xv[nt*16+r] = xg[(((size_t)(b*128+o))<<16) + (size_t)(hw0 + nt*32 + col)];
    }
  }

  const int* slI = (const int*)sl;
  f32x16 acc0=zero16(), acc1=zero16(), acc2=zero16(), acc3=zero16();
  #pragma unroll
  for (int c=0;c<8;++c){
    const int ko = c*16 + (l>>5)*8;
    const int kq = ko>>1;
    const f16x8 a = *(const f16x8*)&wl[wid*32+col][ko];
    auto mkB = [&](int pxb){
      int4 tmp;
      tmp.x = slI[(kq+0)*128 + pxb+col];
      tmp.y = slI[(kq+1)*128 + pxb+col];
      tmp.z = slI[(kq+2)*128 + pxb+col];
      tmp.w = slI[(kq+3)*128 + pxb+col];
      return __builtin_bit_cast(f16x8, tmp);
    };
    acc0 = __builtin_amdgcn_mfma_f32_32x32x16_f16(a, mkB(0),  acc0, 0,0,0);
    acc1 = __builtin_amdgcn_mfma_f32_32x32x16_f16(a, mkB(32), acc1, 0,0,0);
    acc2 = __builtin_amdgcn_mfma_f32_32x32x16_f16(a, mkB(64), acc2, 0,0,0);
    acc3 = __builtin_amdgcn_mfma_f32_32x32x16_f16(a, mkB(96), acc3, 0,0,0);
  }

  auto store2 = [&](const f32x16& A, int nt){
    #pragma unroll
    for (int r=0;r<16;++r){
      const int o = orow + (r&3) + 8*(r>>2);
      const size_t addr = (((size_t)(b*128+o))<<16) + (size_t)(hw0 + nt*32 + col);
      outg[addr] = A[r] + bB[o] + xv[nt*16+r];
    }
  };
  store2(acc0,0); store2(acc1,1); store2(acc2,2); store2(acc3,3);
}

extern "C" void kernel_launch(void* const* d_in, const int* in_sizes, int n_in,
                              void* d_out, int out_size, void* d_ws, size_t ws_size,
                              hipStream_t stream)
{
  (void)in_sizes; (void)n_in; (void)out_size; (void)ws_size;
  const float* x   = (const float*)d_in[0];
  const float* p1w = (const float*)d_in[1];
  const float* p1b = (const float*)d_in[2];
  const float* w1  = (const float*)d_in[3];
  const float* b1  = (const float*)d_in[4];
  const float* w2  = (const float*)d_in[5];
  const float* b2  = (const float*)d_in[6];
  const float* p2w = (const float*)d_in[7];
  const float* p2b = (const float*)d_in[8];
  float* out = (float*)d_out;

  const size_t ST_B = 262144UL*128*2;   // 67,108,864
  // d_out: buf2 [0,67.1M) | h2tp planar [67.1M,134.2M)  (both dead before gemm2 writes)
  // ws   : stp planar [0,67.1M) | nyq plane [67.1M,67.6M)
  __half2* buf2 = (__half2*)d_out;
  __half2* h2tp = (__half2*)((char*)d_out + ST_B);
  __half2* stp  = (__half2*)d_ws;
  __half2* nyq  = (__half2*)((char*)d_ws + ST_B);

  k_gemm1 <<<dim3(2048),     dim3(256), 0, stream>>>(x, p1w, p1b, h2tp);
  k_fftw  <<<dim3(8,64,4),   dim3(256), 0, stream>>>(h2tp, buf2, nyq);
  k_spec  <<<dim3(129,8,4),  dim3(256), 0, stream>>>(buf2, nyq, w1, b1, w2, b2);
  k_ifftw <<<dim3(8,64,4),   dim3(256), 0, stream>>>(buf2, nyq, h2tp, stp);
  k_gemm2 <<<dim3(2048),     dim3(256), 0, stream>>>(stp, p2w, p2b, x, out);
}